// Round 9
// baseline (1971.883 us; speedup 1.0000x reference)
//
#include <hip/hip_runtime.h>
#include <hip/hip_bf16.h>
#include <math.h>

namespace {

constexpr int T = 1024;      // sequence length
constexpr int D = 768;       // model dim
constexpr int FF = 3072;     // ffn dim
constexpr int H = 12;        // heads
constexpr int HD = 64;       // head dim
constexpr int L = 12;        // layers
constexpr float SCALE = 0.125f;                 // 1/sqrt(64), exact power of 2

typedef __attribute__((ext_vector_type(8))) short short8;
typedef __attribute__((ext_vector_type(4))) float floatx4;

__device__ inline unsigned short f2bf(float f) {
    __hip_bfloat16 h = __float2bfloat16(f);   // RNE
    return *reinterpret_cast<unsigned short*>(&h);
}
__device__ inline float bf2f(unsigned short u) {
    union { unsigned int i; float f; } c;
    c.i = (unsigned int)u << 16;
    return c.f;
}

// ---------------- embedding: h0 = wte[ids] + wpe ----------------
__global__ void embed_kernel(const int* __restrict__ ids,
                             const float* __restrict__ wte,
                             const float* __restrict__ wpe,
                             float* __restrict__ h) {
    int i = blockIdx.x * blockDim.x + threadIdx.x;
    if (i >= T * D) return;
    int t = i / D, d = i % D;
    h[i] = wte[(long)ids[t] * D + d] + wpe[i];
}

// ---------------- layernorm (fp32 in, bf16 out), one row per block ----------------
__global__ __launch_bounds__(256)
void ln_kernel(const float* __restrict__ x, const float* __restrict__ g,
               const float* __restrict__ b, unsigned short* __restrict__ out) {
    int row = blockIdx.x, tid = threadIdx.x;
    const float* xr = x + (long)row * D;
    float v0 = xr[tid], v1 = xr[tid + 256], v2 = xr[tid + 512];
    __shared__ float red[4];
    __shared__ float share;
    float s = v0 + v1 + v2;
#pragma unroll
    for (int o = 32; o; o >>= 1) s += __shfl_down(s, o, 64);
    if ((tid & 63) == 0) red[tid >> 6] = s;
    __syncthreads();
    if (tid == 0) share = (red[0] + red[1] + red[2] + red[3]) * (1.0f / D);
    __syncthreads();
    float mu = share;
    float d0 = v0 - mu, d1 = v1 - mu, d2 = v2 - mu;
    float q = d0 * d0 + d1 * d1 + d2 * d2;
#pragma unroll
    for (int o = 32; o; o >>= 1) q += __shfl_down(q, o, 64);
    __syncthreads();
    if ((tid & 63) == 0) red[tid >> 6] = q;
    __syncthreads();
    if (tid == 0) share = rsqrtf((red[0] + red[1] + red[2] + red[3]) * (1.0f / D) + 1e-5f);
    __syncthreads();
    float rs = share;
    unsigned short* orow = out + (long)row * D;
    orow[tid]       = f2bf(d0 * rs * g[tid]       + b[tid]);
    orow[tid + 256] = f2bf(d1 * rs * g[tid + 256] + b[tid + 256]);
    orow[tid + 512] = f2bf(d2 * rs * g[tid + 512] + b[tid + 512]);
}

// ---------------- batched weight transpose+convert: WT[z][n][k] = bf16(W[z][k][n]) ----------------
__global__ __launch_bounds__(256)
void wconvert_b(const float* __restrict__ W, unsigned short* __restrict__ WT,
                int K, int N) {
    const int zl = blockIdx.z;
    W  += (long)zl * K * N;
    WT += (long)zl * N * K;
    __shared__ float t[32][33];
    const int n0 = blockIdx.x * 32, k0 = blockIdx.y * 32;
    const int tx = threadIdx.x, ty = threadIdx.y;
#pragma unroll
    for (int i = 0; i < 4; i++)
        t[ty * 4 + i][tx] = W[(long)(k0 + ty * 4 + i) * N + n0 + tx];
    __syncthreads();
#pragma unroll
    for (int i = 0; i < 4; i++)
        WT[(long)(n0 + ty * 4 + i) * K + k0 + tx] = f2bf(t[tx][ty * 4 + i]);
}

// ---------------- direct-from-L2 bf16 MFMA GEMM core (no LDS, no barriers) ----------------
// Wave-independent 32x64 tiles; lane l holds frag row (l&15), k-off (l>>4)*8
// (layout verified by R5 LDS version). 6x b128 loads + 8 MFMA per K=32 step.
#define DGEMM_CORE(KB, KE)                                                              \
    const int tid = threadIdx.x;                                                        \
    const int w = tid >> 6, lane = tid & 63;                                            \
    const int row0 = blockIdx.y * 128 + w * 32;                                         \
    const int col0 = blockIdx.x * 64;                                                   \
    const int lm = lane & 15, lk = (lane >> 4) * 8;                                     \
    const unsigned short* Ap = A + (long)(row0 + lm) * K + lk;                          \
    const unsigned short* Bp = BT + (long)(col0 + lm) * K + lk;                         \
    const long S16 = 16L * K;                                                           \
    floatx4 acc[2][4] = {};                                                             \
    _Pragma("unroll 4")                                                                 \
    for (int k = (KB); k < (KE); k += 32) {                                             \
        short8 a0 = *(const short8*)(Ap + k);                                           \
        short8 a1 = *(const short8*)(Ap + S16 + k);                                     \
        short8 b0 = *(const short8*)(Bp + k);                                           \
        short8 b1 = *(const short8*)(Bp + S16 + k);                                     \
        short8 b2 = *(const short8*)(Bp + 2 * S16 + k);                                 \
        short8 b3 = *(const short8*)(Bp + 3 * S16 + k);                                 \
        acc[0][0] = __builtin_amdgcn_mfma_f32_16x16x32_bf16(a0, b0, acc[0][0], 0, 0, 0);\
        acc[0][1] = __builtin_amdgcn_mfma_f32_16x16x32_bf16(a0, b1, acc[0][1], 0, 0, 0);\
        acc[0][2] = __builtin_amdgcn_mfma_f32_16x16x32_bf16(a0, b2, acc[0][2], 0, 0, 0);\
        acc[0][3] = __builtin_amdgcn_mfma_f32_16x16x32_bf16(a0, b3, acc[0][3], 0, 0, 0);\
        acc[1][0] = __builtin_amdgcn_mfma_f32_16x16x32_bf16(a1, b0, acc[1][0], 0, 0, 0);\
        acc[1][1] = __builtin_amdgcn_mfma_f32_16x16x32_bf16(a1, b1, acc[1][1], 0, 0, 0);\
        acc[1][2] = __builtin_amdgcn_mfma_f32_16x16x32_bf16(a1, b2, acc[1][2], 0, 0, 0);\
        acc[1][3] = __builtin_amdgcn_mfma_f32_16x16x32_bf16(a1, b3, acc[1][3], 0, 0, 0);\
    }

// fused epilogue: bf16 out. flags: 1=bias, 4=gelu, 16=prescale cols<D by SCALE
// grid (N/64, T/128)
__global__ __launch_bounds__(256)
void gemm_direct(const unsigned short* __restrict__ A, const unsigned short* __restrict__ BT,
                 const float* __restrict__ bias, unsigned short* __restrict__ Cb,
                 int N, int K, int flags) {
    DGEMM_CORE(0, K)
#pragma unroll
    for (int mi = 0; mi < 2; mi++) {
        int rg = row0 + mi * 16 + (lane >> 4) * 4;
#pragma unroll
        for (int ni = 0; ni < 4; ni++) {
            int cg = col0 + ni * 16 + lm;
            float bv = (flags & 1) ? bias[cg] : 0.f;
            float bscale = ((flags & 16) && cg < D) ? SCALE : 1.0f;
#pragma unroll
            for (int r = 0; r < 4; r++) {
                float v = acc[mi][ni][r] + bv;
                if (flags & 4) {
                    float zz = 0.7978845608028654f * (v + 0.044715f * v * v * v);
                    v = v / (1.0f + __expf(-2.0f * zz));
                }
                Cb[(long)(rg + r) * N + cg] = f2bf(v * bscale);
            }
        }
    }
}

// split-K variant: fp32 partials. grid (N/64, T/128, splitK)
__global__ __launch_bounds__(256)
void gemm_direct_sk(const unsigned short* __restrict__ A, const unsigned short* __restrict__ BT,
                    float* __restrict__ part, int N, int K, int splitK) {
    const int z = blockIdx.z;
    const int Kc = K / splitK;
    DGEMM_CORE(z * Kc, z * Kc + Kc)
    float* dst = part + (long)z * T * N;
#pragma unroll
    for (int mi = 0; mi < 2; mi++) {
        int rg = row0 + mi * 16 + (lane >> 4) * 4;
#pragma unroll
        for (int ni = 0; ni < 4; ni++) {
            int cg = col0 + ni * 16 + lm;
#pragma unroll
            for (int r = 0; r < 4; r++)
                dst[(long)(rg + r) * N + cg] = acc[mi][ni][r];
        }
    }
}

// ---------------- split-K reduce + residual + LayerNorm fused ----------------
__global__ __launch_bounds__(256)
void reduce_ln(const float* __restrict__ part, const float* __restrict__ bias,
               const float* __restrict__ resid,
               const float* __restrict__ g, const float* __restrict__ b,
               float* __restrict__ Cres, unsigned short* __restrict__ Cln,
               int splitK) {
    const int row = blockIdx.x, tid = threadIdx.x;
    const int c0 = tid, c1 = tid + 256, c2 = tid + 512;
    const long rb = (long)row * D;
    float v0 = bias[c0] + resid[rb + c0];
    float v1 = bias[c1] + resid[rb + c1];
    float v2 = bias[c2] + resid[rb + c2];
    for (int z = 0; z < splitK; z++) {
        const float* p = part + (long)z * T * D + rb;
        v0 += p[c0]; v1 += p[c1]; v2 += p[c2];
    }
    float* crow = Cres + rb;
    crow[c0] = v0; crow[c1] = v1; crow[c2] = v2;
    __shared__ float red[4];
    __shared__ float share;
    float s = v0 + v1 + v2;
#pragma unroll
    for (int o = 32; o; o >>= 1) s += __shfl_down(s, o, 64);
    if ((tid & 63) == 0) red[tid >> 6] = s;
    __syncthreads();
    if (tid == 0) share = (red[0] + red[1] + red[2] + red[3]) * (1.0f / D);
    __syncthreads();
    float mu = share;
    float d0 = v0 - mu, d1 = v1 - mu, d2 = v2 - mu;
    float q = d0 * d0 + d1 * d1 + d2 * d2;
#pragma unroll
    for (int o = 32; o; o >>= 1) q += __shfl_down(q, o, 64);
    __syncthreads();
    if ((tid & 63) == 0) red[tid >> 6] = q;
    __syncthreads();
    if (tid == 0) share = rsqrtf((red[0] + red[1] + red[2] + red[3]) * (1.0f / D) + 1e-5f);
    __syncthreads();
    float rs = share;
    unsigned short* orow = Cln + rb;
    orow[c0] = f2bf(d0 * rs * g[c0] + b[c0]);
    orow[c1] = f2bf(d1 * rs * g[c1] + b[c1]);
    orow[c2] = f2bf(d2 * rs * g[c2] + b[c2]);
}

// ---------------- MFMA flash attention (bf16 in/out, fp32 softmax state) ----------------
// qkvb: T x 3D bf16 with Q pre-scaled by SCALE. grid (T/64, H), 4 waves.
__global__ __launch_bounds__(256)
void flash_mfma(const unsigned short* __restrict__ qkvb, unsigned short* __restrict__ ctxb) {
    const int h = blockIdx.y;
    const int q0 = blockIdx.x * 64;
    const int tid = threadIdx.x;
    const int w = tid >> 6;
    const int l = tid & 63;
    const int lm = l & 15;
    const int g = l >> 4;

    __shared__ unsigned short Kl[64][72];
    __shared__ unsigned short Vt[64][80];
    __shared__ unsigned short Pl[4][16][72];

    short8 qf[2];
    {
        const unsigned short* qp = qkvb + (long)(q0 + w * 16 + lm) * (3 * D) + h * HD + g * 8;
        qf[0] = *(const short8*)(qp);
        qf[1] = *(const short8*)(qp + 32);
    }

    const int d8 = (tid & 7) * 8;
    const int kp = (tid >> 3) * 2;

    float m = -INFINITY, lsum = 0.f;
    floatx4 o[4] = {};
    const int qw = q0 + w * 16;
    const int nt = blockIdx.x + 1;

    for (int t = 0; t < nt; t++) {
        const int c0 = t * 64;
        __syncthreads();
        {   // stage K row-major, V transposed (bf16 copies/repacks)
            const unsigned short* kr0 = qkvb + (long)(c0 + kp) * (3 * D) + D + h * HD + d8;
            const unsigned short* kr1 = kr0 + 3 * D;
            *(short8*)&Kl[kp][d8]     = *(const short8*)kr0;
            *(short8*)&Kl[kp + 1][d8] = *(const short8*)kr1;
            short8 va = *(const short8*)(kr0 + D);
            short8 vb = *(const short8*)(kr1 + D);
#pragma unroll
            for (int j = 0; j < 8; j++) {
                unsigned int pk = (unsigned)(unsigned short)va[j] |
                                  ((unsigned)(unsigned short)vb[j] << 16);
                *(unsigned int*)&Vt[d8 + j][kp] = pk;
            }
        }
        __syncthreads();

        if (c0 > qw + 15) continue;

        floatx4 st[4] = {};
#pragma unroll
        for (int ks = 0; ks < 2; ks++)
#pragma unroll
            for (int mt = 0; mt < 4; mt++) {
                short8 af = *(const short8*)&Kl[mt * 16 + lm][ks * 32 + g * 8];
                st[mt] = __builtin_amdgcn_mfma_f32_16x16x32_bf16(af, qf[ks], st[mt], 0, 0, 0);
            }

        const int qg = qw + lm;
        if (c0 + 63 > qw) {
#pragma unroll
            for (int mt = 0; mt < 4; mt++)
#pragma unroll
                for (int r = 0; r < 4; r++)
                    if (c0 + mt * 16 + g * 4 + r > qg) st[mt][r] = -INFINITY;
        }
        float tmax = -INFINITY;
#pragma unroll
        for (int mt = 0; mt < 4; mt++)
#pragma unroll
            for (int r = 0; r < 4; r++) tmax = fmaxf(tmax, st[mt][r]);
        tmax = fmaxf(tmax, __shfl_xor(tmax, 16));
        tmax = fmaxf(tmax, __shfl_xor(tmax, 32));
        float mn = fmaxf(m, tmax);
        float alpha = __expf(m - mn);
        float psum = 0.f;
        unsigned short pb[16];
#pragma unroll
        for (int mt = 0; mt < 4; mt++)
#pragma unroll
            for (int r = 0; r < 4; r++) {
                float p = __expf(st[mt][r] - mn);
                psum += p;
                pb[mt * 4 + r] = f2bf(p);
            }
        lsum = lsum * alpha + psum;
        m = mn;
#pragma unroll
        for (int mt = 0; mt < 4; mt++) {
            unsigned int p0 = (unsigned)pb[mt * 4 + 0] | ((unsigned)pb[mt * 4 + 1] << 16);
            unsigned int p1 = (unsigned)pb[mt * 4 + 2] | ((unsigned)pb[mt * 4 + 3] << 16);
            *(unsigned int*)&Pl[w][lm][mt * 16 + g * 4]     = p0;
            *(unsigned int*)&Pl[w][lm][mt * 16 + g * 4 + 2] = p1;
        }
        float ar0 = __shfl(alpha, g * 4 + 0), ar1 = __shfl(alpha, g * 4 + 1);
        float ar2 = __shfl(alpha, g * 4 + 2), ar3 = __shfl(alpha, g * 4 + 3);
#pragma unroll
        for (int fd = 0; fd < 4; fd++) {
            o[fd][0] *= ar0; o[fd][1] *= ar1; o[fd][2] *= ar2; o[fd][3] *= ar3;
        }
#pragma unroll
        for (int ks = 0; ks < 2; ks++) {
            short8 pa = *(const short8*)&Pl[w][lm][ks * 32 + g * 8];
#pragma unroll
            for (int fd = 0; fd < 4; fd++) {
                short8 vb = *(const short8*)&Vt[fd * 16 + lm][ks * 32 + g * 8];
                o[fd] = __builtin_amdgcn_mfma_f32_16x16x32_bf16(pa, vb, o[fd], 0, 0, 0);
            }
        }
    }
    float l2 = lsum + __shfl_xor(lsum, 16);
    float l4 = l2 + __shfl_xor(l2, 32);
    float linv = 1.0f / l4;
    float lr0 = __shfl(linv, g * 4 + 0), lr1 = __shfl(linv, g * 4 + 1);
    float lr2 = __shfl(linv, g * 4 + 2), lr3 = __shfl(linv, g * 4 + 3);
#pragma unroll
    for (int fd = 0; fd < 4; fd++) {
        unsigned short* cp = ctxb + (long)(qw + g * 4) * D + h * HD + fd * 16 + lm;
        cp[0 * D] = f2bf(o[fd][0] * lr0);
        cp[1 * D] = f2bf(o[fd][1] * lr1);
        cp[2 * D] = f2bf(o[fd][2] * lr2);
        cp[3 * D] = f2bf(o[fd][3] * lr3);
    }
}

// ---------------- probe: softmax rows S2 and T-1 per head (bf16 qkvb, Q pre-scaled) ----------------
__global__ __launch_bounds__(256)
void probe_kernel(const unsigned short* __restrict__ qkvb,
                  const int* __restrict__ Sp, const int* __restrict__ Sa1p,
                  const int* __restrict__ S2p,
                  float* __restrict__ out, int layer) {
    const int h = blockIdx.y;
    const int which = blockIdx.x;
    const int s = *Sp, sa1 = *Sa1p, s2 = *S2p;
    const int row = which ? (T - 1) : s2;
    const int tid = threadIdx.x;
    __shared__ float qrow[64];
    __shared__ float prob[T];
    __shared__ float red[4];
    __shared__ float bshare;
    if (tid < 64) qrow[tid] = bf2f(qkvb[(long)row * (3 * D) + h * HD + tid]);
    __syncthreads();
    float mloc = -INFINITY;
    for (int j = tid; j <= row; j += 256) {
        const unsigned short* krow = qkvb + (long)j * (3 * D) + D + h * HD;
        float acc = 0;
#pragma unroll
        for (int d = 0; d < 64; d += 8) {
            short8 kv = *(const short8*)(krow + d);
#pragma unroll
            for (int e = 0; e < 8; e++)
                acc += qrow[d + e] * bf2f((unsigned short)kv[e]);
        }
        prob[j] = acc;   // Q pre-scaled by SCALE (exact pow2)
        mloc = fmaxf(mloc, acc);
    }
#pragma unroll
    for (int o = 32; o; o >>= 1) mloc = fmaxf(mloc, __shfl_down(mloc, o, 64));
    if ((tid & 63) == 0) red[tid >> 6] = mloc;
    __syncthreads();
    if (tid == 0) bshare = fmaxf(fmaxf(red[0], red[1]), fmaxf(red[2], red[3]));
    __syncthreads();
    float m = bshare;
    float ssum = 0;
    for (int j = tid; j <= row; j += 256) {
        float e = expf(prob[j] - m);
        prob[j] = e;
        ssum += e;
    }
#pragma unroll
    for (int o = 32; o; o >>= 1) ssum += __shfl_down(ssum, o, 64);
    __syncthreads();
    if ((tid & 63) == 0) red[tid >> 6] = ssum;
    __syncthreads();
    if (tid == 0) bshare = red[0] + red[1] + red[2] + red[3];
    __syncthreads();
    float inv = 1.0f / bshare;
    if (tid == 0) {
        if (which == 0) {
            out[0 * (L * H) + layer * H + h] = prob[s] * inv;
            out[1 * (L * H) + layer * H + h] = prob[sa1] * inv;
        } else {
            out[2 * (L * H) + layer * H + h] = prob[s2] * inv;
            out[3 * (L * H) + layer * H + h] = prob[s2] * inv;
        }
    }
}

}  // namespace

extern "C" void kernel_launch(void* const* d_in, const int* in_sizes, int n_in,
                              void* d_out, int out_size, void* d_ws, size_t ws_size,
                              hipStream_t stream) {
    const int*   ids    = (const int*)  d_in[0];
    const float* wte    = (const float*)d_in[2];
    const float* wpe    = (const float*)d_in[3];
    const float* ln1_g  = (const float*)d_in[4];
    const float* ln1_b  = (const float*)d_in[5];
    const float* W_qkv  = (const float*)d_in[6];
    const float* b_qkv  = (const float*)d_in[7];
    const float* W_o    = (const float*)d_in[8];
    const float* b_o    = (const float*)d_in[9];
    const float* ln2_g  = (const float*)d_in[10];
    const float* ln2_b  = (const float*)d_in[11];
    const float* W_fc   = (const float*)d_in[12];
    const float* b_fc   = (const float*)d_in[13];
    const float* W_proj = (const float*)d_in[14];
    const float* b_proj = (const float*)d_in[15];
    const int*   Sp     = (const int*)  d_in[16];
    const int*   Sa1p   = (const int*)  d_in[17];
    const int*   S2p    = (const int*)  d_in[18];
    float* out = (float*)d_out;

    float* ws   = (float*)d_ws;
    float* h    = ws;                      // T*D fp32 residual
    float* h2   = h   + (long)T * D;       // T*D fp32
    float* part = h2  + (long)T * D;       // 4*T*D fp32 split partials
    unsigned short* xl   = (unsigned short*)(part + 4L * T * D);   // T*D bf16
    unsigned short* qkvb = xl   + (long)T * D;                     // T*3D bf16 (Q pre-scaled)
    unsigned short* ctxb = qkvb + (long)T * 3 * D;                 // T*D bf16
    unsigned short* fb   = ctxb + (long)T * D;                     // T*FF bf16
    unsigned short* wt_qkv  = fb      + (long)T * FF;
    unsigned short* wt_o    = wt_qkv  + (long)L * 3 * D * D;
    unsigned short* wt_fc   = wt_o    + (long)L * D * D;
    unsigned short* wt_proj = wt_fc   + (long)L * D * FF;

    // upfront: embedding + ALL weight conversions (parallel, batched over layers)
    embed_kernel<<<(T * D + 255) / 256, 256, 0, stream>>>(ids, wte, wpe, h);
    wconvert_b<<<dim3(3 * D / 32, D / 32, L), dim3(32, 8), 0, stream>>>(W_qkv, wt_qkv, D, 3 * D);
    wconvert_b<<<dim3(D / 32, D / 32, L), dim3(32, 8), 0, stream>>>(W_o, wt_o, D, D);
    wconvert_b<<<dim3(FF / 32, D / 32, L), dim3(32, 8), 0, stream>>>(W_fc, wt_fc, D, FF);
    wconvert_b<<<dim3(D / 32, FF / 32, L), dim3(32, 8), 0, stream>>>(W_proj, wt_proj, FF, D);
    // layer-0 ln1 (subsequent LNs fused into reduce_ln)
    ln_kernel<<<T, 256, 0, stream>>>(h, ln1_g, ln1_b, xl);

    for (int l = 0; l < L; l++) {
        // qkvb = bf16(xl @ W_qkv + b_qkv), Q cols pre-scaled by SCALE
        gemm_direct<<<dim3(3 * D / 64, T / 128), 256, 0, stream>>>(
            xl, wt_qkv + (long)l * 3 * D * D, b_qkv + (long)l * 3 * D,
            qkvb, 3 * D, D, 1 | 16);
        probe_kernel<<<dim3(2, H), 256, 0, stream>>>(qkvb, Sp, Sa1p, S2p, out, l);

        if (l == L - 1) break;  // last layer: h_new unused

        // ctx = causal-softmax(QK^T) @ V  (bf16 in/out)
        flash_mfma<<<dim3(T / 64, H), 256, 0, stream>>>(qkvb, ctxb);
        // h2 = h + ctx @ W_o + b_o ; xl = ln2(h2)
        gemm_direct_sk<<<dim3(D / 64, T / 128, 4), 256, 0, stream>>>(
            ctxb, wt_o + (long)l * D * D, part, D, D, 4);
        reduce_ln<<<T, 256, 0, stream>>>(
            part, b_o + (long)l * D, h, ln2_g + l * D, ln2_b + l * D, h2, xl, 4);
        // f = gelu(xl @ W_fc + b_fc)  (bf16 out)
        gemm_direct<<<dim3(FF / 64, T / 128), 256, 0, stream>>>(
            xl, wt_fc + (long)l * D * FF, b_fc + (long)l * FF, fb, FF, D, 1 | 4);
        // h = h2 + f @ W_proj + b_proj ; xl = ln1_{l+1}(h)
        gemm_direct_sk<<<dim3(D / 64, T / 128, 4), 256, 0, stream>>>(
            fb, wt_proj + (long)l * D * FF, part, D, FF, 4);
        reduce_ln<<<T, 256, 0, stream>>>(
            part, b_proj + (long)l * D, h2, ln1_g + (l + 1) * D, ln1_b + (l + 1) * D, h, xl, 4);
    }
}

// Round 10
// 1421.204 us; speedup vs baseline: 1.3875x; 1.3875x over previous
//
#include <hip/hip_runtime.h>
#include <hip/hip_bf16.h>
#include <math.h>

namespace {

constexpr int T = 1024;      // sequence length
constexpr int D = 768;       // model dim
constexpr int FF = 3072;     // ffn dim
constexpr int H = 12;        // heads
constexpr int HD = 64;       // head dim
constexpr int L = 12;        // layers
constexpr float SCALE = 0.125f;                 // 1/sqrt(64), exact power of 2

typedef __attribute__((ext_vector_type(8))) short short8;
typedef __attribute__((ext_vector_type(4))) float floatx4;

__device__ inline unsigned short f2bf(float f) {
    __hip_bfloat16 h = __float2bfloat16(f);   // RNE
    return *reinterpret_cast<unsigned short*>(&h);
}
__device__ inline float bf2f(unsigned short u) {
    union { unsigned int i; float f; } c;
    c.i = (unsigned int)u << 16;
    return c.f;
}

// ---------------- embedding: h0 = wte[ids] + wpe ----------------
__global__ void embed_kernel(const int* __restrict__ ids,
                             const float* __restrict__ wte,
                             const float* __restrict__ wpe,
                             float* __restrict__ h) {
    int i = blockIdx.x * blockDim.x + threadIdx.x;
    if (i >= T * D) return;
    int t = i / D, d = i % D;
    h[i] = wte[(long)ids[t] * D + d] + wpe[i];
}

// ---------------- layernorm (fp32 in, bf16 out), one row per block ----------------
__global__ __launch_bounds__(256)
void ln_kernel(const float* __restrict__ x, const float* __restrict__ g,
               const float* __restrict__ b, unsigned short* __restrict__ out) {
    int row = blockIdx.x, tid = threadIdx.x;
    const float* xr = x + (long)row * D;
    float v0 = xr[tid], v1 = xr[tid + 256], v2 = xr[tid + 512];
    __shared__ float red[4];
    __shared__ float share;
    float s = v0 + v1 + v2;
#pragma unroll
    for (int o = 32; o; o >>= 1) s += __shfl_down(s, o, 64);
    if ((tid & 63) == 0) red[tid >> 6] = s;
    __syncthreads();
    if (tid == 0) share = (red[0] + red[1] + red[2] + red[3]) * (1.0f / D);
    __syncthreads();
    float mu = share;
    float d0 = v0 - mu, d1 = v1 - mu, d2 = v2 - mu;
    float q = d0 * d0 + d1 * d1 + d2 * d2;
#pragma unroll
    for (int o = 32; o; o >>= 1) q += __shfl_down(q, o, 64);
    __syncthreads();
    if ((tid & 63) == 0) red[tid >> 6] = q;
    __syncthreads();
    if (tid == 0) share = rsqrtf((red[0] + red[1] + red[2] + red[3]) * (1.0f / D) + 1e-5f);
    __syncthreads();
    float rs = share;
    unsigned short* orow = out + (long)row * D;
    orow[tid]       = f2bf(d0 * rs * g[tid]       + b[tid]);
    orow[tid + 256] = f2bf(d1 * rs * g[tid + 256] + b[tid + 256]);
    orow[tid + 512] = f2bf(d2 * rs * g[tid + 512] + b[tid + 512]);
}

// ---------------- batched weight transpose+convert: WT[z][n][k] = bf16(W[z][k][n]) ----------------
__global__ __launch_bounds__(256)
void wconvert_b(const float* __restrict__ W, unsigned short* __restrict__ WT,
                int K, int N) {
    const int zl = blockIdx.z;
    W  += (long)zl * K * N;
    WT += (long)zl * N * K;
    __shared__ float t[32][33];
    const int n0 = blockIdx.x * 32, k0 = blockIdx.y * 32;
    const int tx = threadIdx.x, ty = threadIdx.y;
#pragma unroll
    for (int i = 0; i < 4; i++)
        t[ty * 4 + i][tx] = W[(long)(k0 + ty * 4 + i) * N + n0 + tx];
    __syncthreads();
#pragma unroll
    for (int i = 0; i < 4; i++)
        WT[(long)(n0 + ty * 4 + i) * K + k0 + tx] = f2bf(t[tx][ty * 4 + i]);
}

// ---------------- shared GEMM core: 128x64 tile, BK=32, 4 waves, per-wave 32x64 (2x4 frags) ----------------
// LDS staging lane-linear (conflict-free); each thread stages 2 A-slots + 1 B-slot.
// 6 ds_read_b128 : 8 MFMA per wave per K-step (was 4:4 at 64x64 tile).
#define GEMM_CORE(KLEN)                                                                 \
    floatx4 acc[2][4] = {};                                                             \
    {                                                                                   \
        *(short8*)&As[0][ablk][sl][0]     = *(const short8*)(ApA);                      \
        *(short8*)&As[0][ablk + 4][sl][0] = *(const short8*)(ApB);                      \
        *(short8*)&Bs[0][ablk][sl][0]     = *(const short8*)(Bp);                       \
    }                                                                                   \
    __syncthreads();                                                                    \
    const int nsteps = (KLEN) >> 5;                                                     \
    for (int s = 0; s < nsteps; s++) {                                                  \
        const int buf = s & 1;                                                          \
        short8 na0, na1, nbv;                                                           \
        const bool has_next = (s + 1 < nsteps);                                         \
        if (has_next) {                                                                 \
            na0 = *(const short8*)(ApA + (s + 1) * 32);                                 \
            na1 = *(const short8*)(ApB + (s + 1) * 32);                                 \
            nbv = *(const short8*)(Bp + (s + 1) * 32);                                  \
        }                                                                               \
        short8 af[2], bfr[4];                                                           \
        _Pragma("unroll")                                                               \
        for (int mi = 0; mi < 2; mi++)                                                  \
            af[mi] = *(const short8*)&As[buf][w * 2 + mi][lane][0];                     \
        _Pragma("unroll")                                                               \
        for (int ni = 0; ni < 4; ni++)                                                  \
            bfr[ni] = *(const short8*)&Bs[buf][ni][lane][0];                            \
        _Pragma("unroll")                                                               \
        for (int mi = 0; mi < 2; mi++)                                                  \
            _Pragma("unroll")                                                           \
            for (int ni = 0; ni < 4; ni++)                                              \
                acc[mi][ni] = __builtin_amdgcn_mfma_f32_16x16x32_bf16(                  \
                    af[mi], bfr[ni], acc[mi][ni], 0, 0, 0);                             \
        if (has_next) {                                                                 \
            const int nb = buf ^ 1;                                                     \
            *(short8*)&As[nb][ablk][sl][0]     = na0;                                   \
            *(short8*)&As[nb][ablk + 4][sl][0] = na1;                                   \
            *(short8*)&Bs[nb][ablk][sl][0]     = nbv;                                   \
        }                                                                               \
        __syncthreads();                                                                \
    }

#define GEMM_PRELUDE(KOFF)                                                              \
    const int tid = threadIdx.x;                                                        \
    const int w = tid >> 6, lane = tid & 63;                                            \
    const int ablk = tid >> 6;                                                          \
    const int sl = tid & 63;                                                            \
    const int row0 = blockIdx.y * 128, col0 = blockIdx.x * 64;                          \
    __shared__ unsigned short As[2][8][64][8];                                          \
    __shared__ unsigned short Bs[2][4][64][8];                                          \
    const unsigned short* ApA = A + (long)(row0 + ablk * 16 + (sl & 15)) * K + (KOFF) + (sl >> 4) * 8; \
    const unsigned short* ApB = ApA + 64L * K;                                          \
    const unsigned short* Bp  = BT + (long)(col0 + ablk * 16 + (sl & 15)) * K + (KOFF) + (sl >> 4) * 8;

// ---------------- bf16 MFMA GEMM, fused epilogue (no split-K) ----------------
// flags: 1=bias, 4=gelu, 16=prescale cols<D by SCALE. grid (N/64, T/128)
__global__ __launch_bounds__(256)
void gemm_fused(const unsigned short* __restrict__ A, const unsigned short* __restrict__ BT,
                const float* __restrict__ bias, unsigned short* __restrict__ Cb,
                int N, int K, int flags) {
    GEMM_PRELUDE(0)
    GEMM_CORE(K)
#pragma unroll
    for (int mi = 0; mi < 2; mi++) {
        int rg = row0 + (w * 2 + mi) * 16 + (lane >> 4) * 4;
#pragma unroll
        for (int ni = 0; ni < 4; ni++) {
            int cg = col0 + ni * 16 + (lane & 15);
            float bv = (flags & 1) ? bias[cg] : 0.f;
            float bscale = ((flags & 16) && cg < D) ? SCALE : 1.0f;
#pragma unroll
            for (int r = 0; r < 4; r++) {
                float v = acc[mi][ni][r] + bv;
                if (flags & 4) {
                    float zz = 0.7978845608028654f * (v + 0.044715f * v * v * v);
                    v = v / (1.0f + __expf(-2.0f * zz));
                }
                Cb[(long)(rg + r) * N + cg] = f2bf(v * bscale);
            }
        }
    }
}

// ---------------- bf16 MFMA GEMM, split-K, fp32 partials. grid (N/64, T/128, splitK) ----------------
__global__ __launch_bounds__(256)
void gemm_bf16(const unsigned short* __restrict__ A, const unsigned short* __restrict__ BT,
               float* __restrict__ part, int N, int K, int splitK) {
    const int z = blockIdx.z;
    const int Kc = K / splitK;
    GEMM_PRELUDE(z * Kc)
    GEMM_CORE(Kc)
    float* dst = part + (long)z * T * N;
#pragma unroll
    for (int mi = 0; mi < 2; mi++) {
        int rg = row0 + (w * 2 + mi) * 16 + (lane >> 4) * 4;
#pragma unroll
        for (int ni = 0; ni < 4; ni++) {
            int cg = col0 + ni * 16 + (lane & 15);
#pragma unroll
            for (int r = 0; r < 4; r++)
                dst[(long)(rg + r) * N + cg] = acc[mi][ni][r];
        }
    }
}

// ---------------- split-K reduce + residual + LayerNorm fused ----------------
__global__ __launch_bounds__(256)
void reduce_ln(const float* __restrict__ part, const float* __restrict__ bias,
               const float* __restrict__ resid,
               const float* __restrict__ g, const float* __restrict__ b,
               float* __restrict__ Cres, unsigned short* __restrict__ Cln,
               int splitK) {
    const int row = blockIdx.x, tid = threadIdx.x;
    const int c0 = tid, c1 = tid + 256, c2 = tid + 512;
    const long rb = (long)row * D;
    float v0 = bias[c0] + resid[rb + c0];
    float v1 = bias[c1] + resid[rb + c1];
    float v2 = bias[c2] + resid[rb + c2];
    for (int z = 0; z < splitK; z++) {
        const float* p = part + (long)z * T * D + rb;
        v0 += p[c0]; v1 += p[c1]; v2 += p[c2];
    }
    float* crow = Cres + rb;
    crow[c0] = v0; crow[c1] = v1; crow[c2] = v2;
    __shared__ float red[4];
    __shared__ float share;
    float s = v0 + v1 + v2;
#pragma unroll
    for (int o = 32; o; o >>= 1) s += __shfl_down(s, o, 64);
    if ((tid & 63) == 0) red[tid >> 6] = s;
    __syncthreads();
    if (tid == 0) share = (red[0] + red[1] + red[2] + red[3]) * (1.0f / D);
    __syncthreads();
    float mu = share;
    float d0 = v0 - mu, d1 = v1 - mu, d2 = v2 - mu;
    float q = d0 * d0 + d1 * d1 + d2 * d2;
#pragma unroll
    for (int o = 32; o; o >>= 1) q += __shfl_down(q, o, 64);
    __syncthreads();
    if ((tid & 63) == 0) red[tid >> 6] = q;
    __syncthreads();
    if (tid == 0) share = rsqrtf((red[0] + red[1] + red[2] + red[3]) * (1.0f / D) + 1e-5f);
    __syncthreads();
    float rs = share;
    unsigned short* orow = Cln + rb;
    orow[c0] = f2bf(d0 * rs * g[c0] + b[c0]);
    orow[c1] = f2bf(d1 * rs * g[c1] + b[c1]);
    orow[c2] = f2bf(d2 * rs * g[c2] + b[c2]);
}

// ---------------- MFMA flash attention (bf16 in/out, fp32 softmax state) ----------------
// qkvb: T x 3D bf16 with Q pre-scaled by SCALE. grid (T/64, H), 4 waves.
__global__ __launch_bounds__(256)
void flash_mfma(const unsigned short* __restrict__ qkvb, unsigned short* __restrict__ ctxb) {
    const int h = blockIdx.y;
    const int q0 = blockIdx.x * 64;
    const int tid = threadIdx.x;
    const int w = tid >> 6;
    const int l = tid & 63;
    const int lm = l & 15;
    const int g = l >> 4;

    __shared__ unsigned short Kl[64][72];
    __shared__ unsigned short Vt[64][80];
    __shared__ unsigned short Pl[4][16][72];

    short8 qf[2];
    {
        const unsigned short* qp = qkvb + (long)(q0 + w * 16 + lm) * (3 * D) + h * HD + g * 8;
        qf[0] = *(const short8*)(qp);
        qf[1] = *(const short8*)(qp + 32);
    }

    const int d8 = (tid & 7) * 8;
    const int kp = (tid >> 3) * 2;

    float m = -INFINITY, lsum = 0.f;
    floatx4 o[4] = {};
    const int qw = q0 + w * 16;
    const int nt = blockIdx.x + 1;

    for (int t = 0; t < nt; t++) {
        const int c0 = t * 64;
        __syncthreads();
        {   // stage K row-major, V transposed (bf16 copies/repacks)
            const unsigned short* kr0 = qkvb + (long)(c0 + kp) * (3 * D) + D + h * HD + d8;
            const unsigned short* kr1 = kr0 + 3 * D;
            *(short8*)&Kl[kp][d8]     = *(const short8*)kr0;
            *(short8*)&Kl[kp + 1][d8] = *(const short8*)kr1;
            short8 va = *(const short8*)(kr0 + D);
            short8 vb = *(const short8*)(kr1 + D);
#pragma unroll
            for (int j = 0; j < 8; j++) {
                unsigned int pk = (unsigned)(unsigned short)va[j] |
                                  ((unsigned)(unsigned short)vb[j] << 16);
                *(unsigned int*)&Vt[d8 + j][kp] = pk;
            }
        }
        __syncthreads();

        if (c0 > qw + 15) continue;

        floatx4 st[4] = {};
#pragma unroll
        for (int ks = 0; ks < 2; ks++)
#pragma unroll
            for (int mt = 0; mt < 4; mt++) {
                short8 af = *(const short8*)&Kl[mt * 16 + lm][ks * 32 + g * 8];
                st[mt] = __builtin_amdgcn_mfma_f32_16x16x32_bf16(af, qf[ks], st[mt], 0, 0, 0);
            }

        const int qg = qw + lm;
        if (c0 + 63 > qw) {
#pragma unroll
            for (int mt = 0; mt < 4; mt++)
#pragma unroll
                for (int r = 0; r < 4; r++)
                    if (c0 + mt * 16 + g * 4 + r > qg) st[mt][r] = -INFINITY;
        }
        float tmax = -INFINITY;
#pragma unroll
        for (int mt = 0; mt < 4; mt++)
#pragma unroll
            for (int r = 0; r < 4; r++) tmax = fmaxf(tmax, st[mt][r]);
        tmax = fmaxf(tmax, __shfl_xor(tmax, 16));
        tmax = fmaxf(tmax, __shfl_xor(tmax, 32));
        float mn = fmaxf(m, tmax);
        float alpha = __expf(m - mn);
        float psum = 0.f;
        unsigned short pb[16];
#pragma unroll
        for (int mt = 0; mt < 4; mt++)
#pragma unroll
            for (int r = 0; r < 4; r++) {
                float p = __expf(st[mt][r] - mn);
                psum += p;
                pb[mt * 4 + r] = f2bf(p);
            }
        lsum = lsum * alpha + psum;
        m = mn;
#pragma unroll
        for (int mt = 0; mt < 4; mt++) {
            unsigned int p0 = (unsigned)pb[mt * 4 + 0] | ((unsigned)pb[mt * 4 + 1] << 16);
            unsigned int p1 = (unsigned)pb[mt * 4 + 2] | ((unsigned)pb[mt * 4 + 3] << 16);
            *(unsigned int*)&Pl[w][lm][mt * 16 + g * 4]     = p0;
            *(unsigned int*)&Pl[w][lm][mt * 16 + g * 4 + 2] = p1;
        }
        float ar0 = __shfl(alpha, g * 4 + 0), ar1 = __shfl(alpha, g * 4 + 1);
        float ar2 = __shfl(alpha, g * 4 + 2), ar3 = __shfl(alpha, g * 4 + 3);
#pragma unroll
        for (int fd = 0; fd < 4; fd++) {
            o[fd][0] *= ar0; o[fd][1] *= ar1; o[fd][2] *= ar2; o[fd][3] *= ar3;
        }
#pragma unroll
        for (int ks = 0; ks < 2; ks++) {
            short8 pa = *(const short8*)&Pl[w][lm][ks * 32 + g * 8];
#pragma unroll
            for (int fd = 0; fd < 4; fd++) {
                short8 vb = *(const short8*)&Vt[fd * 16 + lm][ks * 32 + g * 8];
                o[fd] = __builtin_amdgcn_mfma_f32_16x16x32_bf16(pa, vb, o[fd], 0, 0, 0);
            }
        }
    }
    float l2 = lsum + __shfl_xor(lsum, 16);
    float l4 = l2 + __shfl_xor(l2, 32);
    float linv = 1.0f / l4;
    float lr0 = __shfl(linv, g * 4 + 0), lr1 = __shfl(linv, g * 4 + 1);
    float lr2 = __shfl(linv, g * 4 + 2), lr3 = __shfl(linv, g * 4 + 3);
#pragma unroll
    for (int fd = 0; fd < 4; fd++) {
        unsigned short* cp = ctxb + (long)(qw + g * 4) * D + h * HD + fd * 16 + lm;
        cp[0 * D] = f2bf(o[fd][0] * lr0);
        cp[1 * D] = f2bf(o[fd][1] * lr1);
        cp[2 * D] = f2bf(o[fd][2] * lr2);
        cp[3 * D] = f2bf(o[fd][3] * lr3);
    }
}

// ---------------- probe: softmax rows S2 and T-1 per head (bf16 qkvb, Q pre-scaled) ----------------
__global__ __launch_bounds__(256)
void probe_kernel(const unsigned short* __restrict__ qkvb,
                  const int* __restrict__ Sp, const int* __restrict__ Sa1p,
                  const int* __restrict__ S2p,
                  float* __restrict__ out, int layer) {
    const int h = blockIdx.y;
    const int which = blockIdx.x;
    const int s = *Sp, sa1 = *Sa1p, s2 = *S2p;
    const int row = which ? (T - 1) : s2;
    const int tid = threadIdx.x;
    __shared__ float qrow[64];
    __shared__ float prob[T];
    __shared__ float red[4];
    __shared__ float bshare;
    if (tid < 64) qrow[tid] = bf2f(qkvb[(long)row * (3 * D) + h * HD + tid]);
    __syncthreads();
    float mloc = -INFINITY;
    for (int j = tid; j <= row; j += 256) {
        const unsigned short* krow = qkvb + (long)j * (3 * D) + D + h * HD;
        float acc = 0;
#pragma unroll
        for (int d = 0; d < 64; d += 8) {
            short8 kv = *(const short8*)(krow + d);
#pragma unroll
            for (int e = 0; e < 8; e++)
                acc += qrow[d + e] * bf2f((unsigned short)kv[e]);
        }
        prob[j] = acc;   // Q pre-scaled by SCALE (exact pow2)
        mloc = fmaxf(mloc, acc);
    }
#pragma unroll
    for (int o = 32; o; o >>= 1) mloc = fmaxf(mloc, __shfl_down(mloc, o, 64));
    if ((tid & 63) == 0) red[tid >> 6] = mloc;
    __syncthreads();
    if (tid == 0) bshare = fmaxf(fmaxf(red[0], red[1]), fmaxf(red[2], red[3]));
    __syncthreads();
    float m = bshare;
    float ssum = 0;
    for (int j = tid; j <= row; j += 256) {
        float e = expf(prob[j] - m);
        prob[j] = e;
        ssum += e;
    }
#pragma unroll
    for (int o = 32; o; o >>= 1) ssum += __shfl_down(ssum, o, 64);
    __syncthreads();
    if ((tid & 63) == 0) red[tid >> 6] = ssum;
    __syncthreads();
    if (tid == 0) bshare = red[0] + red[1] + red[2] + red[3];
    __syncthreads();
    float inv = 1.0f / bshare;
    if (tid == 0) {
        if (which == 0) {
            out[0 * (L * H) + layer * H + h] = prob[s] * inv;
            out[1 * (L * H) + layer * H + h] = prob[sa1] * inv;
        } else {
            out[2 * (L * H) + layer * H + h] = prob[s2] * inv;
            out[3 * (L * H) + layer * H + h] = prob[s2] * inv;
        }
    }
}

}  // namespace

extern "C" void kernel_launch(void* const* d_in, const int* in_sizes, int n_in,
                              void* d_out, int out_size, void* d_ws, size_t ws_size,
                              hipStream_t stream) {
    const int*   ids    = (const int*)  d_in[0];
    const float* wte    = (const float*)d_in[2];
    const float* wpe    = (const float*)d_in[3];
    const float* ln1_g  = (const float*)d_in[4];
    const float* ln1_b  = (const float*)d_in[5];
    const float* W_qkv  = (const float*)d_in[6];
    const float* b_qkv  = (const float*)d_in[7];
    const float* W_o    = (const float*)d_in[8];
    const float* b_o    = (const float*)d_in[9];
    const float* ln2_g  = (const float*)d_in[10];
    const float* ln2_b  = (const float*)d_in[11];
    const float* W_fc   = (const float*)d_in[12];
    const float* b_fc   = (const float*)d_in[13];
    const float* W_proj = (const float*)d_in[14];
    const float* b_proj = (const float*)d_in[15];
    const int*   Sp     = (const int*)  d_in[16];
    const int*   Sa1p   = (const int*)  d_in[17];
    const int*   S2p    = (const int*)  d_in[18];
    float* out = (float*)d_out;

    float* ws   = (float*)d_ws;
    float* h    = ws;                      // T*D fp32 residual
    float* h2   = h   + (long)T * D;       // T*D fp32
    float* part = h2  + (long)T * D;       // 4*T*D fp32 split partials
    unsigned short* xl   = (unsigned short*)(part + 4L * T * D);   // T*D bf16
    unsigned short* qkvb = xl   + (long)T * D;                     // T*3D bf16 (Q pre-scaled)
    unsigned short* ctxb = qkvb + (long)T * 3 * D;                 // T*D bf16
    unsigned short* fb   = ctxb + (long)T * D;                     // T*FF bf16
    unsigned short* wt_qkv  = fb      + (long)T * FF;
    unsigned short* wt_o    = wt_qkv  + (long)L * 3 * D * D;
    unsigned short* wt_fc   = wt_o    + (long)L * D * D;
    unsigned short* wt_proj = wt_fc   + (long)L * D * FF;

    // upfront: embedding + ALL weight conversions (parallel, batched over layers)
    embed_kernel<<<(T * D + 255) / 256, 256, 0, stream>>>(ids, wte, wpe, h);
    wconvert_b<<<dim3(3 * D / 32, D / 32, L), dim3(32, 8), 0, stream>>>(W_qkv, wt_qkv, D, 3 * D);
    wconvert_b<<<dim3(D / 32, D / 32, L), dim3(32, 8), 0, stream>>>(W_o, wt_o, D, D);
    wconvert_b<<<dim3(FF / 32, D / 32, L), dim3(32, 8), 0, stream>>>(W_fc, wt_fc, D, FF);
    wconvert_b<<<dim3(D / 32, FF / 32, L), dim3(32, 8), 0, stream>>>(W_proj, wt_proj, FF, D);
    // layer-0 ln1 (subsequent LNs fused into reduce_ln)
    ln_kernel<<<T, 256, 0, stream>>>(h, ln1_g, ln1_b, xl);

    for (int l = 0; l < L; l++) {
        // qkvb = bf16(xl @ W_qkv + b_qkv), Q cols pre-scaled by SCALE
        gemm_fused<<<dim3(3 * D / 64, T / 128), 256, 0, stream>>>(
            xl, wt_qkv + (long)l * 3 * D * D, b_qkv + (long)l * 3 * D,
            qkvb, 3 * D, D, 1 | 16);
        probe_kernel<<<dim3(2, H), 256, 0, stream>>>(qkvb, Sp, Sa1p, S2p, out, l);

        if (l == L - 1) break;  // last layer: h_new unused

        // ctx = causal-softmax(QK^T) @ V  (bf16 in/out)
        flash_mfma<<<dim3(T / 64, H), 256, 0, stream>>>(qkvb, ctxb);
        // h2 = h + ctx @ W_o + b_o ; xl = ln2(h2)
        gemm_bf16<<<dim3(D / 64, T / 128, 4), 256, 0, stream>>>(
            ctxb, wt_o + (long)l * D * D, part, D, D, 4);
        reduce_ln<<<T, 256, 0, stream>>>(
            part, b_o + (long)l * D, h, ln2_g + l * D, ln2_b + l * D, h2, xl, 4);
        // f = gelu(xl @ W_fc + b_fc)  (bf16 out)
        gemm_fused<<<dim3(FF / 64, T / 128), 256, 0, stream>>>(
            xl, wt_fc + (long)l * D * FF, b_fc + (long)l * FF, fb, FF, D, 1 | 4);
        // h = h2 + f @ W_proj + b_proj ; xl = ln1_{l+1}(h)
        gemm_bf16<<<dim3(D / 64, T / 128, 4), 256, 0, stream>>>(
            fb, wt_proj + (long)l * D * FF, part, D, FF, 4);
        reduce_ln<<<T, 256, 0, stream>>>(
            part, b_proj + (long)l * D, h2, ln1_g + (l + 1) * D, ln1_b + (l + 1) * D, h, xl, 4);
    }
}